// Round 2
// baseline (521.715 us; speedup 1.0000x reference)
//
#include <hip/hip_runtime.h>
#include <hip/hip_bf16.h>

#define NPTS   1024
#define HID    128
#define CHUNK  128
#define NCHUNK (NPTS / CHUNK)
#define LDH    136   // padded k-stride (bf16 elems) for the shared h1 / W2^T tile

typedef __bf16 bf16_t;
typedef __bf16 bf16x8 __attribute__((ext_vector_type(8)));
typedef float  f32x4  __attribute__((ext_vector_type(4)));

__device__ __forceinline__ float fast_exp2(float x) {
#if __has_builtin(__builtin_amdgcn_exp2f)
    return __builtin_amdgcn_exp2f(x);
#else
    return exp2f(x);
#endif
}
__device__ __forceinline__ float fast_rcp(float x) {
#if __has_builtin(__builtin_amdgcn_rcpf)
    return __builtin_amdgcn_rcpf(x);
#else
    return 1.0f / x;
#endif
}
// tanh(x) = 1 - 2/(e^{2x}+1); e^{2x} = 2^{2*log2(e)*x}. Saturates correctly at +-inf.
__device__ __forceinline__ float fast_tanh(float x) {
    float e = fast_exp2(2.8853900817779268f * x);
    return 1.0f - 2.0f * fast_rcp(e + 1.0f);
}

__launch_bounds__(256, 2)
__global__ void discovery_forces(const float* __restrict__ pos,
                                 const float* __restrict__ W1,
                                 const float* __restrict__ b1,
                                 const float* __restrict__ W2,
                                 const float* __restrict__ b2,
                                 const float* __restrict__ W3,
                                 const float* __restrict__ b3,
                                 float* __restrict__ out)
{
    __shared__ __align__(16) bf16_t sA[CHUNK * LDH];   // W2^T staging, then h1 tile (34.8 KB)
    __shared__ float  poss[NPTS * 3];                  // this batch's positions, fp32 (12 KB)
    __shared__ f32x4  feat_s[CHUNK];                   // (dist, 1/r, 1/r^2, -)
    __shared__ f32x4  u_s[CHUNK];                      // unit vectors (diff/dist_clip)
    __shared__ f32x4  mag4[CHUNK / 4];                 // per-j magnitudes
    __shared__ f32x4  w1s[HID];                        // (W1[0,h], W1[1,h], W1[2,h], b1[h])
    __shared__ float  b2s[HID];
    __shared__ float  w3s[HID];
    __shared__ float  wsum[4][3];

    const int t    = threadIdx.x;
    const int blk  = blockIdx.x;
    const int b    = blk >> 10;          // / NPTS
    const int i    = blk & (NPTS - 1);
    const int wave = t >> 6;
    const int lane = t & 63;
    const int ln   = lane & 15;          // MFMA col / row-within-tile selector
    const int q    = lane >> 4;          // MFMA quad

    // ---------------- preamble ----------------
    for (int idx = t; idx < NPTS * 3; idx += 256)
        poss[idx] = pos[b * NPTS * 3 + idx];
    if (t < HID) {
        f32x4 w = { W1[t], W1[HID + t], W1[2 * HID + t], b1[t] };
        w1s[t] = w;
        b2s[t] = b2[t];
        w3s[t] = W3[t];
    }
    // stage W2 transposed (bf16) into sA: sA[n*LDH + k] = W2[k*HID + n]
    for (int idx = t; idx < HID * HID; idx += 256) {
        int k = idx >> 7, n = idx & 127;
        sA[n * LDH + k] = (bf16_t)W2[idx];
    }
    __syncthreads();

    // Build W2 B-fragments in registers (held for the whole kernel).
    // B[k][n] frag: n = nt*16 + ln, k = ks*32 + q*8 + j  (j = vector element)
    bf16x8 wfrag[8][4];
#pragma unroll
    for (int nt = 0; nt < 8; ++nt)
#pragma unroll
        for (int ks = 0; ks < 4; ++ks)
            wfrag[nt][ks] = *(const bf16x8*)&sA[(nt * 16 + ln) * LDH + ks * 32 + q * 8];
    __syncthreads();   // frag reads done before sA is reused as h1

    const float pix = poss[i * 3 + 0];
    const float piy = poss[i * 3 + 1];
    const float piz = poss[i * 3 + 2];
    const float b3v = b3[0];

    float fx = 0.f, fy = 0.f, fz = 0.f;

    for (int c = 0; c < NCHUNK; ++c) {
        // ---- Phase A: pair geometry ----
        if (t < CHUNK) {
            int j = c * CHUNK + t;
            float dx = pix - poss[j * 3 + 0];
            float dy = piy - poss[j * 3 + 1];
            float dz = piz - poss[j * 3 + 2];
            float dist = sqrtf(dx * dx + dy * dy + dz * dz);
            float inv  = 1.0f / fmaxf(dist, 0.01f);
            f32x4 ft = { dist, inv, inv * inv, 0.f };
            f32x4 uv = { dx * inv, dy * inv, dz * inv, 0.f };
            feat_s[t] = ft;
            u_s[t]    = uv;
        }
        __syncthreads();

        // ---- Phase B: h1 = tanh(feat @ W1 + b1), bf16 into sA ----
        {
            int p = t >> 1, half = t & 1;
            f32x4 ft = feat_s[p];
            bf16_t* dst = &sA[p * LDH + half * 64];
#pragma unroll
            for (int g = 0; g < 8; ++g) {
                bf16x8 hb;
#pragma unroll
                for (int e = 0; e < 8; ++e) {
                    f32x4 w = w1s[half * 64 + g * 8 + e];
                    float z = ft[0] * w[0] + ft[1] * w[1] + ft[2] * w[2] + w[3];
                    hb[e] = (bf16_t)fast_tanh(z);
                }
                *(bf16x8*)(dst + g * 8) = hb;
            }
        }
        __syncthreads();

        // ---- Phase C: h2pre = h1 @ W2 (MFMA), then mag = tanh(h2pre+b2) @ W3 + b3 ----
        {
            f32x4 zero = { 0.f, 0.f, 0.f, 0.f };
            f32x4 acc[2][8];
#pragma unroll
            for (int mt = 0; mt < 2; ++mt)
#pragma unroll
                for (int nt = 0; nt < 8; ++nt) acc[mt][nt] = zero;

            const bf16_t* a0base = &sA[(wave * 32 + ln) * LDH];
            const bf16_t* a1base = &sA[(wave * 32 + 16 + ln) * LDH];
#pragma unroll
            for (int ks = 0; ks < 4; ++ks) {
                bf16x8 a0 = *(const bf16x8*)(a0base + ks * 32 + q * 8);
                bf16x8 a1 = *(const bf16x8*)(a1base + ks * 32 + q * 8);
#pragma unroll
                for (int nt = 0; nt < 8; ++nt) {
                    acc[0][nt] = __builtin_amdgcn_mfma_f32_16x16x32_bf16(a0, wfrag[nt][ks], acc[0][nt], 0, 0, 0);
                    acc[1][nt] = __builtin_amdgcn_mfma_f32_16x16x32_bf16(a1, wfrag[nt][ks], acc[1][nt], 0, 0, 0);
                }
            }

            float pm0[4] = {0.f, 0.f, 0.f, 0.f};
            float pm1[4] = {0.f, 0.f, 0.f, 0.f};
#pragma unroll
            for (int nt = 0; nt < 8; ++nt) {
                float b2n = b2s[nt * 16 + ln];
                float w3n = w3s[nt * 16 + ln];
#pragma unroll
                for (int r = 0; r < 4; ++r) {
                    pm0[r] += fast_tanh(acc[0][nt][r] + b2n) * w3n;
                    pm1[r] += fast_tanh(acc[1][nt][r] + b2n) * w3n;
                }
            }
            // reduce over the 16 lanes sharing a quad-group (xor of bits 0..3)
#pragma unroll
            for (int off = 1; off < 16; off <<= 1) {
#pragma unroll
                for (int r = 0; r < 4; ++r) {
                    pm0[r] += __shfl_xor(pm0[r], off);
                    pm1[r] += __shfl_xor(pm1[r], off);
                }
            }
            if (ln == 0) {
                f32x4 v0 = { pm0[0] + b3v, pm0[1] + b3v, pm0[2] + b3v, pm0[3] + b3v };
                f32x4 v1 = { pm1[0] + b3v, pm1[1] + b3v, pm1[2] + b3v, pm1[3] + b3v };
                mag4[wave * 8 + q]     = v0;   // rows wave*32 + q*4 ..
                mag4[wave * 8 + 4 + q] = v1;   // rows wave*32 + 16 + q*4 ..
            }
        }
        __syncthreads();

        // ---- Phase D: force accumulation (mask is implicit: u=0 when i==j) ----
        if (t < CHUNK) {
            f32x4 u = u_s[t];
            float m = ((const float*)mag4)[t];
            fx += m * u[0];
            fy += m * u[1];
            fz += m * u[2];
        }
        __syncthreads();
    }

    // ---------------- block reduction ----------------
#pragma unroll
    for (int off = 1; off < 64; off <<= 1) {
        fx += __shfl_xor(fx, off);
        fy += __shfl_xor(fy, off);
        fz += __shfl_xor(fz, off);
    }
    if (lane == 0) { wsum[wave][0] = fx; wsum[wave][1] = fy; wsum[wave][2] = fz; }
    __syncthreads();
    if (t == 0) {
        float ox = wsum[0][0] + wsum[1][0] + wsum[2][0] + wsum[3][0];
        float oy = wsum[0][1] + wsum[1][1] + wsum[2][1] + wsum[3][1];
        float oz = wsum[0][2] + wsum[1][2] + wsum[2][2] + wsum[3][2];
        int o = (b * NPTS + i) * 3;
        out[o + 0] = ox;
        out[o + 1] = oy;
        out[o + 2] = oz;
    }
}

extern "C" void kernel_launch(void* const* d_in, const int* in_sizes, int n_in,
                              void* d_out, int out_size, void* d_ws, size_t ws_size,
                              hipStream_t stream) {
    const float* pos = (const float*)d_in[0];
    const float* W1  = (const float*)d_in[1];
    const float* b1  = (const float*)d_in[2];
    const float* W2  = (const float*)d_in[3];
    const float* b2  = (const float*)d_in[4];
    const float* W3  = (const float*)d_in[5];
    const float* b3  = (const float*)d_in[6];
    float* out = (float*)d_out;

    int grid = in_sizes[0] / 3;   // B * N blocks, one per (b, i)
    discovery_forces<<<grid, 256, 0, stream>>>(pos, W1, b1, W2, b2, W3, b3, out);
}

// Round 3
// 325.041 us; speedup vs baseline: 1.6051x; 1.6051x over previous
//
#include <hip/hip_runtime.h>
#include <hip/hip_bf16.h>

#define NPTS   1024
#define HID    128
#define TS     32                 // tile side (points)
#define NT     (NPTS / TS)        // 32 tiles per dim
#define NPAIR  (NT * (NT + 1) / 2)  // 528 upper-triangle tile pairs per batch
#define CHUNK  128                // pairs per GEMM chunk (4 i-rows x 32 j)
#define NCHUNK (TS * TS / CHUNK)  // 8 chunks per block
#define LDH    136                // padded k-stride (bf16 elems) for h1 / W2^T tile

typedef __bf16 bf16_t;
typedef __bf16 bf16x8 __attribute__((ext_vector_type(8)));
typedef float  f32x4  __attribute__((ext_vector_type(4)));

__device__ __forceinline__ float fast_exp2(float x) {
#if __has_builtin(__builtin_amdgcn_exp2f)
    return __builtin_amdgcn_exp2f(x);
#else
    return exp2f(x);
#endif
}
__device__ __forceinline__ float fast_rcp(float x) {
#if __has_builtin(__builtin_amdgcn_rcpf)
    return __builtin_amdgcn_rcpf(x);
#else
    return 1.0f / x;
#endif
}
// tanh(x) = 1 - 2/(e^{2x}+1); e^{2x} = 2^{2*log2(e)*x}. Saturates correctly.
__device__ __forceinline__ float fast_tanh(float x) {
    float e = fast_exp2(2.8853900817779268f * x);
    return 1.0f - 2.0f * fast_rcp(e + 1.0f);
}

__global__ void zero_out(float* __restrict__ out, int n) {
    int i = blockIdx.x * 256 + threadIdx.x;
    if (i < n) out[i] = 0.0f;
}

__launch_bounds__(256, 2)
__global__ void discovery_forces(const float* __restrict__ pos,
                                 const float* __restrict__ W1,
                                 const float* __restrict__ b1,
                                 const float* __restrict__ W2,
                                 const float* __restrict__ b2,
                                 const float* __restrict__ W3,
                                 const float* __restrict__ b3,
                                 float* __restrict__ out)
{
    __shared__ __align__(16) bf16_t sA[CHUNK * LDH];   // W2^T staging, then h1 tile (34.8 KB)
    __shared__ float  posi[TS * 3], posj[TS * 3];      // tile positions, fp32
    __shared__ f32x4  feat_s[CHUNK];                   // (dist, 1/r, 1/r^2, -)
    __shared__ f32x4  u_s[CHUNK];                      // diff/dist_clip
    __shared__ f32x4  mag4[CHUNK / 4];                 // per-pair magnitudes
    __shared__ f32x4  w1s[HID];                        // (W1[0,h], W1[1,h], W1[2,h], b1[h])
    __shared__ float  b2s[HID];
    __shared__ float  w3s[HID];
    __shared__ float  fjp[4][TS][3];                   // j-side partials (per chunk-row r)

    const int t    = threadIdx.x;
    const int wave = t >> 6;
    const int lane = t & 63;
    const int ln   = lane & 15;          // MFMA col / row-within-tile selector
    const int q    = lane >> 4;          // MFMA quad

    // block -> (b, ti, tj) with ti <= tj (upper triangle of tile pairs)
    const int b = blockIdx.x / NPAIR;
    int p = blockIdx.x % NPAIR;
    int ti = 0, span = NT;
    while (p >= span) { p -= span; ti++; span--; }
    const int tj = ti + p;
    const int gb = b * NPTS;             // batch point base
    const int i0 = ti * TS, j0 = tj * TS;

    // ---------------- preamble ----------------
    if (t < TS * 3)
        posi[t] = pos[(gb + i0) * 3 + t];
    else if (t < 2 * TS * 3)
        posj[t - TS * 3] = pos[(gb + j0) * 3 + (t - TS * 3)];
    if (t < HID) {
        f32x4 w = { W1[t], W1[HID + t], W1[2 * HID + t], b1[t] };
        w1s[t] = w;
        b2s[t] = b2[t];
        w3s[t] = W3[t];
    }
    // stage W2 transposed (bf16) into sA: sA[n*LDH + k] = W2[k*HID + n]
    for (int idx = t; idx < HID * HID; idx += 256) {
        int k = idx >> 7, n = idx & 127;
        sA[n * LDH + k] = (bf16_t)W2[idx];
    }
    __syncthreads();

    // W2 B-fragments in registers, held for the whole kernel.
    // B[k][n]: n = nt*16 + ln, k = ks*32 + q*8 + j
    bf16x8 wfrag[8][4];
#pragma unroll
    for (int nt = 0; nt < 8; ++nt)
#pragma unroll
        for (int ks = 0; ks < 4; ++ks)
            wfrag[nt][ks] = *(const bf16x8*)&sA[(nt * 16 + ln) * LDH + ks * 32 + q * 8];
    __syncthreads();   // frag reads done before sA is reused as h1

    const float b3v = b3[0];
    float fjx = 0.f, fjy = 0.f, fjz = 0.f;   // j-side accumulator (threads 0..127)

    for (int c = 0; c < NCHUNK; ++c) {
        // ---- Phase A: pair geometry. pair p = (r = p>>5, jj = p&31), i-row = c*4+r ----
        if (t < CHUNK) {
            int r = t >> 5, jj = t & 31;
            int ri = c * 4 + r;
            float dx = posi[ri * 3 + 0] - posj[jj * 3 + 0];
            float dy = posi[ri * 3 + 1] - posj[jj * 3 + 1];
            float dz = posi[ri * 3 + 2] - posj[jj * 3 + 2];
            float dist = sqrtf(dx * dx + dy * dy + dz * dz);
            float inv  = 1.0f / fmaxf(dist, 0.01f);
            f32x4 ft = { dist, inv, inv * inv, 0.f };
            f32x4 uv = { dx * inv, dy * inv, dz * inv, 0.f };
            feat_s[t] = ft;
            u_s[t]    = uv;
        }
        __syncthreads();

        // ---- Phase B: h1 = tanh(feat @ W1 + b1), bf16 into sA ----
        {
            int pr = t >> 1, half = t & 1;
            f32x4 ft = feat_s[pr];
            bf16_t* dst = &sA[pr * LDH + half * 64];
#pragma unroll
            for (int g = 0; g < 8; ++g) {
                bf16x8 hb;
#pragma unroll
                for (int e = 0; e < 8; ++e) {
                    f32x4 w = w1s[half * 64 + g * 8 + e];
                    float z = ft[0] * w[0] + ft[1] * w[1] + ft[2] * w[2] + w[3];
                    hb[e] = (bf16_t)fast_tanh(z);
                }
                *(bf16x8*)(dst + g * 8) = hb;
            }
        }
        __syncthreads();

        // ---- Phase C: h2pre = h1 @ W2 (MFMA); mag = tanh(h2pre+b2) @ W3 + b3 ----
        {
            f32x4 zero = { 0.f, 0.f, 0.f, 0.f };
            f32x4 acc[2][8];
#pragma unroll
            for (int mt = 0; mt < 2; ++mt)
#pragma unroll
                for (int nt = 0; nt < 8; ++nt) acc[mt][nt] = zero;

            const bf16_t* a0base = &sA[(wave * 32 + ln) * LDH];
            const bf16_t* a1base = &sA[(wave * 32 + 16 + ln) * LDH];
#pragma unroll
            for (int ks = 0; ks < 4; ++ks) {
                bf16x8 a0 = *(const bf16x8*)(a0base + ks * 32 + q * 8);
                bf16x8 a1 = *(const bf16x8*)(a1base + ks * 32 + q * 8);
#pragma unroll
                for (int nt = 0; nt < 8; ++nt) {
                    acc[0][nt] = __builtin_amdgcn_mfma_f32_16x16x32_bf16(a0, wfrag[nt][ks], acc[0][nt], 0, 0, 0);
                    acc[1][nt] = __builtin_amdgcn_mfma_f32_16x16x32_bf16(a1, wfrag[nt][ks], acc[1][nt], 0, 0, 0);
                }
            }

            float pm0[4] = {0.f, 0.f, 0.f, 0.f};
            float pm1[4] = {0.f, 0.f, 0.f, 0.f};
#pragma unroll
            for (int nt = 0; nt < 8; ++nt) {
                float b2n = b2s[nt * 16 + ln];
                float w3n = w3s[nt * 16 + ln];
#pragma unroll
                for (int r = 0; r < 4; ++r) {
                    pm0[r] += fast_tanh(acc[0][nt][r] + b2n) * w3n;
                    pm1[r] += fast_tanh(acc[1][nt][r] + b2n) * w3n;
                }
            }
#pragma unroll
            for (int off = 1; off < 16; off <<= 1) {
#pragma unroll
                for (int r = 0; r < 4; ++r) {
                    pm0[r] += __shfl_xor(pm0[r], off);
                    pm1[r] += __shfl_xor(pm1[r], off);
                }
            }
            if (ln == 0) {
                f32x4 v0 = { pm0[0] + b3v, pm0[1] + b3v, pm0[2] + b3v, pm0[3] + b3v };
                f32x4 v1 = { pm1[0] + b3v, pm1[1] + b3v, pm1[2] + b3v, pm1[3] + b3v };
                mag4[wave * 8 + q]     = v0;   // rows wave*32 + q*4 ..
                mag4[wave * 8 + 4 + q] = v1;   // rows wave*32 + 16 + q*4 ..
            }
        }
        __syncthreads();

        // ---- Phase D: force accumulation (self-pair contributes 0 since u=0) ----
        if (t < CHUNK) {
            f32x4 u = u_s[t];
            float m = ((const float*)mag4)[t];
            float sx = m * u[0], sy = m * u[1], sz = m * u[2];
            fjx -= sx; fjy -= sy; fjz -= sz;             // j-side (Newton's 3rd law)
            // i-side: reduce over the 32 j-lanes of this i-row
#pragma unroll
            for (int off = 1; off < 32; off <<= 1) {
                sx += __shfl_xor(sx, off);
                sy += __shfl_xor(sy, off);
                sz += __shfl_xor(sz, off);
            }
            if ((lane & 31) == 0) {
                int gi3 = (gb + i0 + c * 4 + (t >> 5)) * 3;
                atomicAdd(&out[gi3 + 0], sx);
                atomicAdd(&out[gi3 + 1], sy);
                atomicAdd(&out[gi3 + 2], sz);
            }
        }
        __syncthreads();
    }

    // ---------------- j-side combine + atomics (skip for diagonal tiles) ----------------
    if (t < CHUNK) {
        int r = t >> 5, jj = t & 31;
        fjp[r][jj][0] = fjx;
        fjp[r][jj][1] = fjy;
        fjp[r][jj][2] = fjz;
    }
    __syncthreads();
    if (t < TS && ti != tj) {
        float ax = fjp[0][t][0] + fjp[1][t][0] + fjp[2][t][0] + fjp[3][t][0];
        float ay = fjp[0][t][1] + fjp[1][t][1] + fjp[2][t][1] + fjp[3][t][1];
        float az = fjp[0][t][2] + fjp[1][t][2] + fjp[2][t][2] + fjp[3][t][2];
        int gj3 = (gb + j0 + t) * 3;
        atomicAdd(&out[gj3 + 0], ax);
        atomicAdd(&out[gj3 + 1], ay);
        atomicAdd(&out[gj3 + 2], az);
    }
}

extern "C" void kernel_launch(void* const* d_in, const int* in_sizes, int n_in,
                              void* d_out, int out_size, void* d_ws, size_t ws_size,
                              hipStream_t stream) {
    const float* pos = (const float*)d_in[0];
    const float* W1  = (const float*)d_in[1];
    const float* b1  = (const float*)d_in[2];
    const float* W2  = (const float*)d_in[3];
    const float* b2  = (const float*)d_in[4];
    const float* W3  = (const float*)d_in[5];
    const float* b3  = (const float*)d_in[6];
    float* out = (float*)d_out;

    int B = (in_sizes[0] / 3) / NPTS;
    zero_out<<<(out_size + 255) / 256, 256, 0, stream>>>(out, out_size);
    discovery_forces<<<B * NPAIR, 256, 0, stream>>>(pos, W1, b1, W2, b2, W3, b3, out);
}

// Round 4
// 93.282 us; speedup vs baseline: 5.5929x; 3.4845x over previous
//
#include <hip/hip_runtime.h>

#define NPTS  1024
#define HID   128
#define K_TAB 4096
#define U0f   (-10.0f)
#define U1f   (4.0f)

__device__ __forceinline__ float fast_exp2(float x) {
#if __has_builtin(__builtin_amdgcn_exp2f)
    return __builtin_amdgcn_exp2f(x);
#else
    return exp2f(x);
#endif
}
__device__ __forceinline__ float fast_rcp(float x) {
#if __has_builtin(__builtin_amdgcn_rcpf)
    return __builtin_amdgcn_rcpf(x);
#else
    return 1.0f / x;
#endif
}
__device__ __forceinline__ float fast_log2(float x) {
#if __has_builtin(__builtin_amdgcn_logf)
    return __builtin_amdgcn_logf(x);
#else
    return __log2f(x);
#endif
}
__device__ __forceinline__ float fast_rsq(float x) {
#if __has_builtin(__builtin_amdgcn_rsqf)
    return __builtin_amdgcn_rsqf(x);
#else
    return rsqrtf(x);
#endif
}
// tanh(x) = 1 - 2/(e^{2x}+1). Saturates correctly at +-inf. ~1e-7 abs err.
__device__ __forceinline__ float fast_tanh(float x) {
    float e = fast_exp2(2.8853900817779268f * x);
    return 1.0f - 2.0f * fast_rcp(e + 1.0f);
}

// ---------------------------------------------------------------------------
// Kernel 1: build mag(d) lookup table. mag is a univariate function of dist
// (feat = (d, 1/clip, 1/clip^2) all derive from d). Grid uniform in log2(d),
// d in [2^-10, 2^4]. Each block computes 32 table entries + 1 halo entry so
// it can emit (value, slope) float2 pairs with no cross-block dependency.
// One wave per entry per r-iteration; fp32 throughout.
// ---------------------------------------------------------------------------
__global__ __launch_bounds__(256) void build_table(const float* __restrict__ W1,
                                                   const float* __restrict__ b1,
                                                   const float* __restrict__ W2,
                                                   const float* __restrict__ b2,
                                                   const float* __restrict__ W3,
                                                   const float* __restrict__ b3,
                                                   float2* __restrict__ tab)
{
    __shared__ float W2s[HID * HID];   // 64 KB, fp32
    __shared__ float h1s[4][HID];
    __shared__ float mag_s[36];

    const int t = threadIdx.x, wave = t >> 6, lane = t & 63;

    for (int idx = t; idx < HID * HID; idx += 256) W2s[idx] = W2[idx];

    // per-lane constants: layer-1 rows for hidden units lane, lane+64;
    // layer-2/3 params for units 2*lane, 2*lane+1
    const float w10a = W1[lane],      w11a = W1[HID + lane],      w12a = W1[2 * HID + lane],      b1a = b1[lane];
    const float w10b = W1[lane + 64], w11b = W1[HID + lane + 64], w12b = W1[2 * HID + lane + 64], b1b = b1[lane + 64];
    const float2 b2l = ((const float2*)b2)[lane];
    const float2 w3l = ((const float2*)W3)[lane];
    const float  b3v = b3[0];
    const float  dU  = (U1f - U0f) / (float)(K_TAB - 1);
    const int    e0  = blockIdx.x * 32;

    __syncthreads();   // W2s staged

    for (int r = 0; r < 9; ++r) {
        int  ei    = wave + 4 * r;        // 0..35
        bool valid = (ei <= 32);          // 33 entries: 32 owned + 1 halo
        if (valid) {
            float u    = U0f + (float)(e0 + ei) * dU;
            float d    = fast_exp2(u);
            float invc = 1.0f / fmaxf(d, 0.01f);
            float inv2 = invc * invc;
            float za = fmaf(d, w10a, fmaf(invc, w11a, fmaf(inv2, w12a, b1a)));
            float zb = fmaf(d, w10b, fmaf(invc, w11b, fmaf(inv2, w12b, b1b)));
            h1s[wave][lane]      = fast_tanh(za);
            h1s[wave][lane + 64] = fast_tanh(zb);
        }
        __syncthreads();   // uniform: h1s visible (also orders vs prev iter reads)
        if (valid) {
            float a0 = b2l.x, a1 = b2l.y;
#pragma unroll 8
            for (int k = 0; k < HID; ++k) {
                float  h = h1s[wave][k];                      // broadcast, conflict-free
                float2 w = ((const float2*)W2s)[k * 64 + lane]; // cols 2l,2l+1 of row k
                a0 = fmaf(h, w.x, a0);
                a1 = fmaf(h, w.y, a1);
            }
            float part = fast_tanh(a0) * w3l.x + fast_tanh(a1) * w3l.y;
#pragma unroll
            for (int off = 1; off < 64; off <<= 1) part += __shfl_xor(part, off);
            if (lane == 0) mag_s[ei] = part + b3v;
        }
        __syncthreads();   // uniform: mag_s written; h1s safe to overwrite
    }

    if (t < 32) {
        int e = e0 + t;
        tab[e] = make_float2(mag_s[t], mag_s[t + 1] - mag_s[t]);
    }
}

// ---------------------------------------------------------------------------
// Kernel 2: forces. One wave per (b, i); 4 i's per block. Per pair: r^2,
// u = 0.5*log2(r^2) (no sqrt), table lerp, f += mag * diff * min(rsqrt,100).
// Self-pair contributes 0 (diff = 0). Output written exactly once -> no
// zeroing kernel, no atomics.
// ---------------------------------------------------------------------------
__global__ __launch_bounds__(256) void forces_kernel(const float* __restrict__ pos,
                                                     const float2* __restrict__ tab,
                                                     float* __restrict__ out)
{
    __shared__ float2 tab_s[K_TAB];      // 32 KB
    __shared__ float  pos_s[NPTS * 3];   // 12 KB

    const int t = threadIdx.x, wave = t >> 6, lane = t & 63;
    const int b  = blockIdx.x >> 8;      // 256 blocks per batch
    const int ig = blockIdx.x & 255;
    const int i  = ig * 4 + wave;

    // stage positions (768 float4) and table (2048 float4)
    {
        const float4* gp = (const float4*)(pos + b * NPTS * 3);
        float4* sp = (float4*)pos_s;
        for (int idx = t; idx < 768; idx += 256) sp[idx] = gp[idx];
        const float4* gt = (const float4*)tab;
        float4* st = (float4*)tab_s;
        for (int idx = t; idx < 2048; idx += 256) st[idx] = gt[idx];
    }
    __syncthreads();

    const float pix = pos_s[i * 3 + 0];
    const float piy = pos_s[i * 3 + 1];
    const float piz = pos_s[i * 3 + 2];
    const float S   = (float)(K_TAB - 1) / (U1f - U0f);

    float fx = 0.f, fy = 0.f, fz = 0.f;
#pragma unroll 4
    for (int j = lane; j < NPTS; j += 64) {
        float dx = pix - pos_s[j * 3 + 0];
        float dy = piy - pos_s[j * 3 + 1];
        float dz = piz - pos_s[j * 3 + 2];
        float r2 = fmaf(dx, dx, fmaf(dy, dy, dz * dz));
        float u  = 0.5f * fast_log2(r2);               // r2=0 -> -inf -> clamps to k=0
        float tt = (u - U0f) * S;
        float kf = fminf(fmaxf(floorf(tt), 0.0f), (float)(K_TAB - 2));
        float fr = fminf(fmaxf(tt - kf, 0.0f), 1.0f);
        int   k  = (int)kf;
        float2 te = tab_s[k];
        float mag  = fmaf(te.y, fr, te.x);
        float invd = fminf(fast_rsq(r2), 100.0f);      // 1/max(d, 0.01); rsq(0)=inf -> 100
        float s = mag * invd;
        fx = fmaf(s, dx, fx);
        fy = fmaf(s, dy, fy);
        fz = fmaf(s, dz, fz);
    }
#pragma unroll
    for (int off = 1; off < 64; off <<= 1) {
        fx += __shfl_xor(fx, off);
        fy += __shfl_xor(fy, off);
        fz += __shfl_xor(fz, off);
    }
    if (lane == 0) {
        int o = (b * NPTS + i) * 3;
        out[o + 0] = fx;
        out[o + 1] = fy;
        out[o + 2] = fz;
    }
}

extern "C" void kernel_launch(void* const* d_in, const int* in_sizes, int n_in,
                              void* d_out, int out_size, void* d_ws, size_t ws_size,
                              hipStream_t stream) {
    const float* pos = (const float*)d_in[0];
    const float* W1  = (const float*)d_in[1];
    const float* b1  = (const float*)d_in[2];
    const float* W2  = (const float*)d_in[3];
    const float* b2  = (const float*)d_in[4];
    const float* W3  = (const float*)d_in[5];
    const float* b3  = (const float*)d_in[6];
    float* out = (float*)d_out;

    float2* tab = (float2*)d_ws;   // 32 KB scratch

    int B = (in_sizes[0] / 3) / NPTS;
    build_table<<<K_TAB / 32, 256, 0, stream>>>(W1, b1, W2, b2, W3, b3, tab);
    forces_kernel<<<B * 256, 256, 0, stream>>>(pos, tab, out);
}